// Round 4
// baseline (142416.907 us; speedup 1.0000x reference)
//
#include <hip/hip_runtime.h>
#include <stdint.h>

typedef unsigned long long u64;

#define SPS   2048            // samples = time steps per spin
#define NSPIN 32
#define H     512
#define NSTEP (SPS*NSPIN)     // 65536 recurrence steps
#define TPB   512
#define NL    3
#define LB    32              // blocks per layer
#define RPB   16              // rows per block (H / LB)
#define HEAD  (NL*LB)         // head block id = 96
#define NB    (NL*LB + 1)     // 97 blocks

__device__ __forceinline__ u64 ld_agent(const u64* p){
  return __hip_atomic_load(p, __ATOMIC_RELAXED, __HIP_MEMORY_SCOPE_AGENT);
}
__device__ __forceinline__ void st_agent(u64* p, u64 v){
  __hip_atomic_store(p, v, __ATOMIC_RELAXED, __HIP_MEMORY_SCOPE_AGENT);
}
__device__ __forceinline__ unsigned ldu_agent(const unsigned* p){
  return __hip_atomic_load(p, __ATOMIC_RELAXED, __HIP_MEMORY_SCOPE_AGENT);
}
__device__ __forceinline__ void stu_agent(unsigned* p, unsigned v){
  __hip_atomic_store(p, v, __ATOMIC_RELAXED, __HIP_MEMORY_SCOPE_AGENT);
}

// Spin until the 8B packet at p carries `tag` in its high word; return payload.
// Tag rides with the value in one atomic 8B load => no fence needed.
__device__ __forceinline__ float poll_pkt(const u64* p, unsigned tag){
  u64 v = ld_agent(p);
  int n = 0;
  while ((unsigned)(v >> 32) != tag){
    if (++n > 8) __builtin_amdgcn_s_sleep(1);
    v = ld_agent(p);
    if (n > (1<<22)) break;   // bail instead of hanging the harness
  }
  return __uint_as_float((unsigned)(v & 0xffffffffu));
}

__global__ void init_prog(unsigned* prog){
  for (int j = threadIdx.x; j < NB*16; j += 512) prog[j] = 0;
}

__global__ __launch_bounds__(TPB, 2)
void rnn_pipeline(const int* __restrict__ samples,
                  const float* __restrict__ Wih0, const float* __restrict__ Whh0,
                  const float* __restrict__ bih0, const float* __restrict__ bhh0,
                  const float* __restrict__ Wih,  const float* __restrict__ Whh,
                  const float* __restrict__ bih,  const float* __restrict__ bhh,
                  const float* __restrict__ Wd,   const float* __restrict__ bd,
                  float* __restrict__ out,
                  u64* __restrict__ ring, unsigned* __restrict__ prog,
                  int depth)
{
  const int bid = blockIdx.x;
  const int tid = threadIdx.x;
  const int dmask = depth - 1;

  __shared__ __align__(16) float lds_h[2][H];  // staged h(u-1), dbuf
  __shared__ __align__(16) float lds_y[2][H];  // staged y_{l-1}(u)
  __shared__ int   lds_bits[SPS];              // sample bits for current spin
  __shared__ float lds_acc[SPS];               // head: probability products
  __shared__ float lds_red[2][2][8];           // head: per-wave dot partials

  if (bid == HEAD){
    // ------------------------------ head ------------------------------
    for (int tt = tid; tt < SPS; tt += TPB) lds_acc[tt] = 1.0f;
    __syncthreads();
    u64* ring2 = ring + (size_t)2*depth*H;
    const int w = tid >> 6, lane = tid & 63;
    float wd0=0.f, wd1=0.f, b0=0.f, b1=0.f;
    for (int u = 0; u < NSTEP; ++u){
      const int i = u >> 11, t = u & (SPS-1), par = u & 1;
      if ((u & (SPS-1)) == 0){
        __syncthreads();                       // quiesce readers of lds_bits
        for (int tt = tid; tt < SPS; tt += TPB)
          lds_bits[tt] = samples[tt*NSPIN + i];
        wd0 = Wd[((size_t)i*2+0)*H + tid];
        wd1 = Wd[((size_t)i*2+1)*H + tid];
        b0 = bd[i*2+0]; b1 = bd[i*2+1];
      }
      const float y = poll_pkt(&ring2[(size_t)(u & dmask)*H + tid], (unsigned)(u+1));
      if (tid == 511 && (u & 31) == 31) stu_agent(&prog[HEAD*16], (unsigned)(u+1));
      float p0 = wd0*y, p1 = wd1*y;
      #pragma unroll
      for (int o = 32; o > 0; o >>= 1){
        p0 += __shfl_down(p0, o);
        p1 += __shfl_down(p1, o);
      }
      if (lane == 0){ lds_red[par][0][w] = p0; lds_red[par][1][w] = p1; }
      __syncthreads();
      if (tid == 0){
        float z0 = b0, z1 = b1;
        #pragma unroll
        for (int q = 0; q < 8; ++q){ z0 += lds_red[par][0][q]; z1 += lds_red[par][1][q]; }
        const float m  = fmaxf(z0, z1);
        const float e0 = expf(z0 - m), e1 = expf(z1 - m);
        lds_acc[t] *= (lds_bits[t] ? e1 : e0) / (e0 + e1);
      }
    }
    if (tid == 511) stu_agent(&prog[HEAD*16], (unsigned)NSTEP);
    __syncthreads();
    for (int tt = tid; tt < SPS; tt += TPB) out[tt] = lds_acc[tt];
    return;
  }

  // ------------------------------ layers ------------------------------
  const int layer = bid >> 5;            // bid / 32
  const int g     = bid & 31;
  const int c     = tid & 31;            // 16-float col chunk index
  const int sub   = tid >> 5;            // row within block (0..15)
  const int row   = g*RPB + sub;
  const bool leader = (c == 0);
  const bool has_wi = (layer > 0);
  u64* ringL  = ring + (size_t)layer*depth*H;
  u64* ringIn = ring + (size_t)(layer > 0 ? layer-1 : 0)*depth*H;
  const int rot = (c >> 2) & 3;          // bank-swizzle rotation for this lane

  float wh[16], wi[16];                  // 16(+16) weights/thread: register-resident
  float bsum = 0.f, w0c = 0.f, w1c = 0.f;

  for (int u = 0; u < NSTEP; ++u){
    const int i = u >> 11, t = u & (SPS-1), par = u & 1;

    // -------- spin boundary: weights (pre-rotated), biases, sample bits ----
    if ((u & (SPS-1)) == 0){
      __syncthreads();                   // protect lds_bits readers
      if (layer == 0 && i > 0){
        for (int tt = tid; tt < SPS; tt += TPB)
          lds_bits[tt] = samples[tt*NSPIN + (i-1)];
      }
      const float* wrow = (layer == 0)
        ? Whh0 + ((size_t)i*H + row)*H
        : Whh  + (((size_t)i*(NL-1) + (layer-1))*H + row)*H;
      #pragma unroll
      for (int jj = 0; jj < 4; ++jj){
        const int s = (jj + rot) & 3;    // rotation baked into load order
        const float4 v = *(const float4*)(wrow + c*16 + s*4);
        wh[4*jj+0]=v.x; wh[4*jj+1]=v.y; wh[4*jj+2]=v.z; wh[4*jj+3]=v.w;
      }
      if (has_wi){
        const float* irow = Wih + (((size_t)i*(NL-1) + (layer-1))*H + row)*H;
        #pragma unroll
        for (int jj = 0; jj < 4; ++jj){
          const int s = (jj + rot) & 3;
          const float4 v = *(const float4*)(irow + c*16 + s*4);
          wi[4*jj+0]=v.x; wi[4*jj+1]=v.y; wi[4*jj+2]=v.z; wi[4*jj+3]=v.w;
        }
      }
      if (leader){
        if (layer == 0){
          bsum = bih0[i*H + row] + bhh0[i*H + row];
          w0c  = Wih0[((size_t)i*H + row)*2 + 0];
          w1c  = Wih0[((size_t)i*H + row)*2 + 1];
        } else {
          bsum = bih[((size_t)i*(NL-1)+(layer-1))*H + row]
               + bhh[((size_t)i*(NL-1)+(layer-1))*H + row];
        }
      }
    }

    // -------- dual poll: h(u-1) and y(u), both loads in flight --------
    {
      const u64* ph = &ringL[(size_t)((u-1) & dmask)*H + tid];
      const u64* pq = &ringIn[(size_t)(u & dmask)*H + tid];
      const bool needh = (u > 0);
      const unsigned tagh = (unsigned)u, tagy = (unsigned)(u+1);
      u64 vh = needh  ? ld_agent(ph) : 0;
      u64 vy = has_wi ? ld_agent(pq) : 0;
      bool okh = !needh, oky = !has_wi;
      float rh = 0.f, ry = 0.f;
      int n = 0;
      for (;;){
        if (!okh && (unsigned)(vh >> 32) == tagh){ okh = true; rh = __uint_as_float((unsigned)vh); }
        if (!oky && (unsigned)(vy >> 32) == tagy){ oky = true; ry = __uint_as_float((unsigned)vy); }
        if (okh && oky) break;
        if (++n > 8) __builtin_amdgcn_s_sleep(1);
        if (!okh) vh = ld_agent(ph);
        if (!oky) vy = ld_agent(pq);
        if (n > (1<<22)) break;
      }
      lds_h[par][tid] = rh;
      if (has_wi) lds_y[par][tid] = ry;
    }

    // progress + backpressure on non-critical lanes
    if (tid == 510 && (u & 31) == 31) stu_agent(&prog[bid*16], (unsigned)(u+1));
    if (tid == 509 && (u & 63) == 0 && (u + 64) > depth){
      const unsigned need = (unsigned)(u + 64 - depth);
      const int cfirst = (layer < 2) ? (layer+1)*LB : HEAD;
      const int ccount = (layer < 2) ? LB : 1;
      int guard = 0;
      for (;;){
        unsigned mn = 0xffffffffu;
        for (int q = 0; q < ccount; ++q){
          const unsigned pv = ldu_agent(&prog[(cfirst+q)*16]);
          mn = pv < mn ? pv : mn;
        }
        if (mn >= need) break;
        __builtin_amdgcn_s_sleep(8);
        if (++guard > (1<<20)) break;
      }
    }

    __syncthreads();

    // -------- dot over this thread's 16-col chunk (swizzled LDS reads) ------
    const float* hbase = &lds_h[par][c*16];
    float a0=0.f, a1=0.f, a2=0.f, a3=0.f;
    #pragma unroll
    for (int jj = 0; jj < 4; ++jj){
      const int s = (jj + rot) & 3;
      const float4 hv = *(const float4*)(hbase + s*4);
      a0 = fmaf(wh[4*jj+0], hv.x, a0); a1 = fmaf(wh[4*jj+1], hv.y, a1);
      a2 = fmaf(wh[4*jj+2], hv.z, a2); a3 = fmaf(wh[4*jj+3], hv.w, a3);
    }
    if (has_wi){
      const float* ybase = &lds_y[par][c*16];
      #pragma unroll
      for (int jj = 0; jj < 4; ++jj){
        const int s = (jj + rot) & 3;
        const float4 yv = *(const float4*)(ybase + s*4);
        a0 = fmaf(wi[4*jj+0], yv.x, a0); a1 = fmaf(wi[4*jj+1], yv.y, a1);
        a2 = fmaf(wi[4*jj+2], yv.z, a2); a3 = fmaf(wi[4*jj+3], yv.w, a3);
      }
    }
    // reduce across the 32 lanes of this row group (offsets stay in-group)
    float p = (a0 + a1) + (a2 + a3);
    p += __shfl_down(p, 16);
    p += __shfl_down(p, 8);
    p += __shfl_down(p, 4);
    p += __shfl_down(p, 2);
    p += __shfl_down(p, 1);

    if (leader){
      float s = p + bsum;
      if (layer == 0 && i > 0) s += lds_bits[t] ? w1c : w0c;
      const float hv = tanhf(s);
      st_agent(&ringL[(size_t)(u & dmask)*H + row],
               ((u64)(unsigned)(u+1) << 32) | (u64)__float_as_uint(hv));
    }
  }
  if (tid == 510) stu_agent(&prog[bid*16], (unsigned)NSTEP);
}

extern "C" void kernel_launch(void* const* d_in, const int* in_sizes, int n_in,
                              void* d_out, int out_size, void* d_ws, size_t ws_size,
                              hipStream_t stream)
{
  const int*   samples = (const int*)  d_in[0];
  const float* Wih0    = (const float*)d_in[1];
  const float* Whh0    = (const float*)d_in[2];
  const float* bih0    = (const float*)d_in[3];
  const float* bhh0    = (const float*)d_in[4];
  const float* Wih     = (const float*)d_in[5];
  const float* Whh     = (const float*)d_in[6];
  const float* bih     = (const float*)d_in[7];
  const float* bhh     = (const float*)d_in[8];
  const float* Wd      = (const float*)d_in[9];
  const float* bd      = (const float*)d_in[10];

  int depth = 256;   // ring depth (steps); shrink if workspace is small
  while (depth > 2 && (size_t)3*depth*H*sizeof(u64) + 8192 > ws_size) depth >>= 1;

  u64*      ring = (u64*)d_ws;
  unsigned* prog = (unsigned*)((char*)d_ws + (size_t)3*depth*H*sizeof(u64));

  init_prog<<<1, 512, 0, stream>>>(prog);
  rnn_pipeline<<<NB, TPB, 0, stream>>>(samples, Wih0, Whh0, bih0, bhh0,
                                       Wih, Whh, bih, bhh, Wd, bd,
                                       (float*)d_out, ring, prog, depth);
}

// Round 5
// 111067.871 us; speedup vs baseline: 1.2823x; 1.2823x over previous
//
#include <hip/hip_runtime.h>
#include <stdint.h>

typedef unsigned long long u64;

#define SPS   2048            // samples = time steps per spin
#define NSPIN 32
#define H     512
#define NSTEP (SPS*NSPIN)     // 65536 recurrence steps
#define TPB   512
#define NL    3
#define LB    32              // blocks per layer
#define RPB   16              // rows per block (H / LB)
#define HEAD  (NL*LB)         // head block id = 96
#define NB    (NL*LB + 1)     // 97 blocks

__device__ __forceinline__ u64 ld_agent(const u64* p){
  return __hip_atomic_load(p, __ATOMIC_RELAXED, __HIP_MEMORY_SCOPE_AGENT);
}
__device__ __forceinline__ void st_agent(u64* p, u64 v){
  __hip_atomic_store(p, v, __ATOMIC_RELAXED, __HIP_MEMORY_SCOPE_AGENT);
}
__device__ __forceinline__ unsigned ldu_agent(const unsigned* p){
  return __hip_atomic_load(p, __ATOMIC_RELAXED, __HIP_MEMORY_SCOPE_AGENT);
}
__device__ __forceinline__ void stu_agent(unsigned* p, unsigned v){
  __hip_atomic_store(p, v, __ATOMIC_RELAXED, __HIP_MEMORY_SCOPE_AGENT);
}

// Spin until the 8B packet at p carries `tag` in its high word; return payload.
// Tag rides with the value in one atomic 8B load => no fence needed.
__device__ __forceinline__ float poll_pkt(const u64* p, unsigned tag){
  u64 v = ld_agent(p);
  int n = 0;
  while ((unsigned)(v >> 32) != tag){
    if (++n > 8) __builtin_amdgcn_s_sleep(1);
    v = ld_agent(p);
    if (n > (1<<22)) break;   // bail instead of hanging the harness
  }
  return __uint_as_float((unsigned)(v & 0xffffffffu));
}

__global__ void init_prog(unsigned* prog){
  for (int j = threadIdx.x; j < NB*16; j += 512) prog[j] = 0;
}

__global__ __launch_bounds__(TPB, 2)
void rnn_pipeline(const int* __restrict__ samples,
                  const float* __restrict__ Wih0, const float* __restrict__ Whh0,
                  const float* __restrict__ bih0, const float* __restrict__ bhh0,
                  const float* __restrict__ Wih,  const float* __restrict__ Whh,
                  const float* __restrict__ bih,  const float* __restrict__ bhh,
                  const float* __restrict__ Wd,   const float* __restrict__ bd,
                  float* __restrict__ out,
                  u64* __restrict__ ring, unsigned* __restrict__ prog,
                  int depth)
{
  const int bid = blockIdx.x;
  const int tid = threadIdx.x;
  const int dmask = depth - 1;

  __shared__ __align__(16) float lds_h[2][H];  // staged h(u-1), dbuf
  __shared__ __align__(16) float lds_y[2][H];  // staged y_{l-1}(u)
  __shared__ float lds_res[RPB];               // leader results -> coalesced store
  __shared__ int   lds_bits[SPS];              // sample bits for current spin
  __shared__ float lds_acc[SPS];               // head: probability products
  __shared__ float lds_red[2][2][8];           // head: per-wave dot partials

  if (bid == HEAD){
    // ------------------------------ head ------------------------------
    for (int tt = tid; tt < SPS; tt += TPB) lds_acc[tt] = 1.0f;
    __syncthreads();
    u64* ring2 = ring + (size_t)2*depth*H;
    const int w = tid >> 6, lane = tid & 63;
    float wd0=0.f, wd1=0.f, b0=0.f, b1=0.f;
    for (int u = 0; u < NSTEP; ++u){
      const int i = u >> 11, t = u & (SPS-1), par = u & 1;
      if ((u & (SPS-1)) == 0){
        __syncthreads();                       // quiesce readers of lds_bits
        for (int tt = tid; tt < SPS; tt += TPB)
          lds_bits[tt] = samples[tt*NSPIN + i];
        wd0 = Wd[((size_t)i*2+0)*H + tid];
        wd1 = Wd[((size_t)i*2+1)*H + tid];
        b0 = bd[i*2+0]; b1 = bd[i*2+1];
      }
      const float y = poll_pkt(&ring2[(size_t)(u & dmask)*H + tid], (unsigned)(u+1));
      if (tid == 511 && (u & 31) == 31) stu_agent(&prog[HEAD*16], (unsigned)(u+1));
      float p0 = wd0*y, p1 = wd1*y;
      #pragma unroll
      for (int o = 32; o > 0; o >>= 1){
        p0 += __shfl_down(p0, o);
        p1 += __shfl_down(p1, o);
      }
      if (lane == 0){ lds_red[par][0][w] = p0; lds_red[par][1][w] = p1; }
      __syncthreads();
      if (tid == 0){
        float z0 = b0, z1 = b1;
        #pragma unroll
        for (int q = 0; q < 8; ++q){ z0 += lds_red[par][0][q]; z1 += lds_red[par][1][q]; }
        const float m  = fmaxf(z0, z1);
        const float e0 = expf(z0 - m), e1 = expf(z1 - m);
        lds_acc[t] *= (lds_bits[t] ? e1 : e0) / (e0 + e1);
      }
    }
    if (tid == 511) stu_agent(&prog[HEAD*16], (unsigned)NSTEP);
    __syncthreads();
    for (int tt = tid; tt < SPS; tt += TPB) out[tt] = lds_acc[tt];
    return;
  }

  // ------------------------------ layers ------------------------------
  const int layer = bid >> 5;            // bid / 32
  const int g     = bid & 31;
  const int c     = tid & 31;            // 16-float col chunk index
  const int sub   = tid >> 5;            // row within block (0..15)
  const int row   = g*RPB + sub;
  const bool leader = (c == 0);
  const bool has_wi = (layer > 0);
  u64* ringL  = ring + (size_t)layer*depth*H;
  u64* ringIn = ring + (size_t)(layer > 0 ? layer-1 : 0)*depth*H;
  const int rot = (c >> 2) & 3;          // bank-swizzle rotation for this lane

  float wh[16], wi[16];                  // 16(+16) weights/thread: register-resident
  float bsum = 0.f, w0c = 0.f, w1c = 0.f;

  for (int u = 0; u < NSTEP; ++u){
    const int i = u >> 11, t = u & (SPS-1), par = u & 1;

    // -------- spin boundary: weights (pre-rotated), biases, sample bits ----
    if ((u & (SPS-1)) == 0){
      __syncthreads();                   // protect lds_bits readers
      if (layer == 0 && i > 0){
        for (int tt = tid; tt < SPS; tt += TPB)
          lds_bits[tt] = samples[tt*NSPIN + (i-1)];
      }
      const float* wrow = (layer == 0)
        ? Whh0 + ((size_t)i*H + row)*H
        : Whh  + (((size_t)i*(NL-1) + (layer-1))*H + row)*H;
      #pragma unroll
      for (int jj = 0; jj < 4; ++jj){
        const int s = (jj + rot) & 3;    // rotation baked into load order
        const float4 v = *(const float4*)(wrow + c*16 + s*4);
        wh[4*jj+0]=v.x; wh[4*jj+1]=v.y; wh[4*jj+2]=v.z; wh[4*jj+3]=v.w;
      }
      if (has_wi){
        const float* irow = Wih + (((size_t)i*(NL-1) + (layer-1))*H + row)*H;
        #pragma unroll
        for (int jj = 0; jj < 4; ++jj){
          const int s = (jj + rot) & 3;
          const float4 v = *(const float4*)(irow + c*16 + s*4);
          wi[4*jj+0]=v.x; wi[4*jj+1]=v.y; wi[4*jj+2]=v.z; wi[4*jj+3]=v.w;
        }
      }
      if (leader){
        if (layer == 0){
          bsum = bih0[i*H + row] + bhh0[i*H + row];
          w0c  = Wih0[((size_t)i*H + row)*2 + 0];
          w1c  = Wih0[((size_t)i*H + row)*2 + 1];
        } else {
          bsum = bih[((size_t)i*(NL-1)+(layer-1))*H + row]
               + bhh[((size_t)i*(NL-1)+(layer-1))*H + row];
        }
      }
    }

    // -------- dual poll: h(u-1) and y(u), both loads in flight --------
    {
      const u64* ph = &ringL[(size_t)((u-1) & dmask)*H + tid];
      const u64* pq = &ringIn[(size_t)(u & dmask)*H + tid];
      const bool needh = (u > 0);
      const unsigned tagh = (unsigned)u, tagy = (unsigned)(u+1);
      u64 vh = needh  ? ld_agent(ph) : 0;
      u64 vy = has_wi ? ld_agent(pq) : 0;
      bool okh = !needh, oky = !has_wi;
      float rh = 0.f, ry = 0.f;
      int n = 0;
      for (;;){
        if (!okh && (unsigned)(vh >> 32) == tagh){ okh = true; rh = __uint_as_float((unsigned)vh); }
        if (!oky && (unsigned)(vy >> 32) == tagy){ oky = true; ry = __uint_as_float((unsigned)vy); }
        if (okh && oky) break;
        if (++n > 8) __builtin_amdgcn_s_sleep(1);
        if (!okh) vh = ld_agent(ph);
        if (!oky) vy = ld_agent(pq);
        if (n > (1<<22)) break;
      }
      lds_h[par][tid] = rh;
      if (has_wi) lds_y[par][tid] = ry;
    }

    // progress + backpressure on non-critical lanes
    if (tid == 510 && (u & 31) == 31) stu_agent(&prog[bid*16], (unsigned)(u+1));
    if (tid == 509 && (u & 63) == 0 && (u + 64) > depth){
      const unsigned need = (unsigned)(u + 64 - depth);
      const int cfirst = (layer < 2) ? (layer+1)*LB : HEAD;
      const int ccount = (layer < 2) ? LB : 1;
      int guard = 0;
      for (;;){
        unsigned mn = 0xffffffffu;
        for (int q = 0; q < ccount; ++q){
          const unsigned pv = ldu_agent(&prog[(cfirst+q)*16]);
          mn = pv < mn ? pv : mn;
        }
        if (mn >= need) break;
        __builtin_amdgcn_s_sleep(8);
        if (++guard > (1<<20)) break;
      }
    }

    __syncthreads();   // barrier A: staged h/y ready

    // -------- dot over this thread's 16-col chunk (swizzled LDS reads) ------
    const float* hbase = &lds_h[par][c*16];
    float a0=0.f, a1=0.f, a2=0.f, a3=0.f;
    #pragma unroll
    for (int jj = 0; jj < 4; ++jj){
      const int s = (jj + rot) & 3;
      const float4 hv = *(const float4*)(hbase + s*4);
      a0 = fmaf(wh[4*jj+0], hv.x, a0); a1 = fmaf(wh[4*jj+1], hv.y, a1);
      a2 = fmaf(wh[4*jj+2], hv.z, a2); a3 = fmaf(wh[4*jj+3], hv.w, a3);
    }
    if (has_wi){
      const float* ybase = &lds_y[par][c*16];
      #pragma unroll
      for (int jj = 0; jj < 4; ++jj){
        const int s = (jj + rot) & 3;
        const float4 yv = *(const float4*)(ybase + s*4);
        a0 = fmaf(wi[4*jj+0], yv.x, a0); a1 = fmaf(wi[4*jj+1], yv.y, a1);
        a2 = fmaf(wi[4*jj+2], yv.z, a2); a3 = fmaf(wi[4*jj+3], yv.w, a3);
      }
    }
    // reduce across the 32 lanes of this row group (offsets stay in-group)
    float p = (a0 + a1) + (a2 + a3);
    p += __shfl_down(p, 16);
    p += __shfl_down(p, 8);
    p += __shfl_down(p, 4);
    p += __shfl_down(p, 2);
    p += __shfl_down(p, 1);

    if (leader){
      float s = p + bsum;
      if (layer == 0 && i > 0) s += lds_bits[t] ? w1c : w0c;
      lds_res[sub] = tanhf(s);           // stage result for coalesced store
    }
    __syncthreads();   // barrier B: lds_res ready

    // ONE wave-instruction stores the block's whole 128B ring segment:
    // each L3 line written exactly once per step -> no line ping-pong.
    if (tid < RPB){
      st_agent(&ringL[(size_t)(u & dmask)*H + g*RPB + tid],
               ((u64)(unsigned)(u+1) << 32) | (u64)__float_as_uint(lds_res[tid]));
    }
  }
  if (tid == 510) stu_agent(&prog[bid*16], (unsigned)NSTEP);
}

extern "C" void kernel_launch(void* const* d_in, const int* in_sizes, int n_in,
                              void* d_out, int out_size, void* d_ws, size_t ws_size,
                              hipStream_t stream)
{
  const int*   samples = (const int*)  d_in[0];
  const float* Wih0    = (const float*)d_in[1];
  const float* Whh0    = (const float*)d_in[2];
  const float* bih0    = (const float*)d_in[3];
  const float* bhh0    = (const float*)d_in[4];
  const float* Wih     = (const float*)d_in[5];
  const float* Whh     = (const float*)d_in[6];
  const float* bih     = (const float*)d_in[7];
  const float* bhh     = (const float*)d_in[8];
  const float* Wd      = (const float*)d_in[9];
  const float* bd      = (const float*)d_in[10];

  int depth = 256;   // ring depth (steps); shrink if workspace is small
  while (depth > 2 && (size_t)3*depth*H*sizeof(u64) + 8192 > ws_size) depth >>= 1;

  u64*      ring = (u64*)d_ws;
  unsigned* prog = (unsigned*)((char*)d_ws + (size_t)3*depth*H*sizeof(u64));

  init_prog<<<1, 512, 0, stream>>>(prog);
  rnn_pipeline<<<NB, TPB, 0, stream>>>(samples, Wih0, Whh0, bih0, bhh0,
                                       Wih, Whh, bih, bhh, Wd, bd,
                                       (float*)d_out, ring, prog, depth);
}